// Round 1
// baseline (1426.520 us; speedup 1.0000x reference)
//
#include <hip/hip_runtime.h>
#include <hip/hip_bf16.h>
#include <math.h>

// Problem constants
#define EMBED 256
#define KDIM  512   // 2*EMBED
#define BATCH 256
#define SEQ   1024

// GEMM tiling
#define BM 128
#define BN 128
#define BK 16

// Y[r, e] = relu( sum_f X[r, f] * W[e, f] + bias[e] ),  X: R x 512, W: 256 x 512, Y: R x 256
// If tok != nullptr (level 1), X is synthesized from the embedding table:
//   X[r, f] = relu(emb[ tok[2r + (f>>8)] * 256 + (f & 255) ])
__global__ __launch_bounds__(256) void gemm_relu_kernel(
    const float* __restrict__ X,
    const float* __restrict__ W,
    const float* __restrict__ bias,
    float* __restrict__ Y,
    const int* __restrict__ tok,
    const float* __restrict__ emb)
{
    __shared__ float Xs[BK][BM];
    __shared__ float Ws[BK][BN];

    const int tid = threadIdx.x;          // 0..255
    const int m0 = blockIdx.x * BM;
    const int n0 = blockIdx.y * BN;
    const int tn = tid & 15;              // 0..15
    const int tm = tid >> 4;              // 0..15

    float acc[8][8] = {};

    for (int k0 = 0; k0 < KDIM; k0 += BK) {
        // ---- stage X tile (BM rows x BK k) and W tile (BN cols x BK k), transposed to [k][m] ----
        #pragma unroll
        for (int j = 0; j < 2; ++j) {
            const int li  = j * 256 + tid;     // 0..511 float4 slots
            const int row = li >> 2;           // 0..127
            const int kc  = (li & 3) * 4;      // 0,4,8,12

            float4 v;
            if (tok) {
                const int t = tok[2 * (m0 + row) + (k0 >> 8)];
                v = *(const float4*)&emb[(size_t)t * EMBED + (k0 & 255) + kc];
                v.x = fmaxf(v.x, 0.f); v.y = fmaxf(v.y, 0.f);
                v.z = fmaxf(v.z, 0.f); v.w = fmaxf(v.w, 0.f);
            } else {
                v = *(const float4*)&X[(size_t)(m0 + row) * KDIM + k0 + kc];
            }
            Xs[kc + 0][row] = v.x; Xs[kc + 1][row] = v.y;
            Xs[kc + 2][row] = v.z; Xs[kc + 3][row] = v.w;

            const float4 w = *(const float4*)&W[(size_t)(n0 + row) * KDIM + k0 + kc];
            Ws[kc + 0][row] = w.x; Ws[kc + 1][row] = w.y;
            Ws[kc + 2][row] = w.z; Ws[kc + 3][row] = w.w;
        }
        __syncthreads();

        // ---- inner product over the BK slice ----
        #pragma unroll
        for (int k = 0; k < BK; ++k) {
            float a[8], b[8];
            *(float4*)&a[0] = *(const float4*)&Xs[k][tm * 8];
            *(float4*)&a[4] = *(const float4*)&Xs[k][tm * 8 + 4];
            *(float4*)&b[0] = *(const float4*)&Ws[k][tn * 8];
            *(float4*)&b[4] = *(const float4*)&Ws[k][tn * 8 + 4];
            #pragma unroll
            for (int i = 0; i < 8; ++i)
                #pragma unroll
                for (int jj = 0; jj < 8; ++jj)
                    acc[i][jj] = fmaf(a[i], b[jj], acc[i][jj]);
        }
        __syncthreads();
    }

    // ---- epilogue: bias + relu + store ----
    const int col0 = n0 + tn * 8;
    float bv[8];
    #pragma unroll
    for (int j = 0; j < 8; ++j) bv[j] = bias[col0 + j];

    #pragma unroll
    for (int i = 0; i < 8; ++i) {
        const int row = m0 + tm * 8 + i;
        float4 v0, v1;
        v0.x = fmaxf(acc[i][0] + bv[0], 0.f);
        v0.y = fmaxf(acc[i][1] + bv[1], 0.f);
        v0.z = fmaxf(acc[i][2] + bv[2], 0.f);
        v0.w = fmaxf(acc[i][3] + bv[3], 0.f);
        v1.x = fmaxf(acc[i][4] + bv[4], 0.f);
        v1.y = fmaxf(acc[i][5] + bv[5], 0.f);
        v1.z = fmaxf(acc[i][6] + bv[6], 0.f);
        v1.w = fmaxf(acc[i][7] + bv[7], 0.f);
        *(float4*)&Y[(size_t)row * EMBED + col0]     = v0;
        *(float4*)&Y[(size_t)row * EMBED + col0 + 4] = v1;
    }
}

// One wave per batch row: logits = root @ P_w^T + P_b; prediction = argmax; loss = lse - logit[label]
__global__ __launch_bounds__(64) void head_kernel(
    const float* __restrict__ X,     // 256 x 256 (level-10 output)
    const float* __restrict__ Pw,    // 2 x 256
    const float* __restrict__ Pb,    // 2
    const int* __restrict__ labels,  // 256
    float* __restrict__ out)         // [0..255]=prediction (as float), [256..511]=loss
{
    const int b = blockIdx.x;
    const int lane = threadIdx.x;    // 0..63

    float s0 = 0.f, s1 = 0.f;
    #pragma unroll
    for (int i = 0; i < 4; ++i) {
        const int e = lane + i * 64;
        const float x = X[(size_t)b * EMBED + e];
        s0 = fmaf(x, Pw[e], s0);
        s1 = fmaf(x, Pw[EMBED + e], s1);
    }
    #pragma unroll
    for (int off = 32; off > 0; off >>= 1) {
        s0 += __shfl_down(s0, off);
        s1 += __shfl_down(s1, off);
    }
    if (lane == 0) {
        const float l0 = s0 + Pb[0];
        const float l1 = s1 + Pb[1];
        const int pred = (l1 > l0) ? 1 : 0;       // tie -> index 0, matches argmax
        const float m = fmaxf(l0, l1);
        const float lse = m + logf(expf(l0 - m) + expf(l1 - m));
        const int lab = labels[b];
        const float loss = lse - (lab ? l1 : l0);
        out[b] = (float)pred;
        out[BATCH + b] = loss;
    }
}

extern "C" void kernel_launch(void* const* d_in, const int* in_sizes, int n_in,
                              void* d_out, int out_size, void* d_ws, size_t ws_size,
                              hipStream_t stream)
{
    const int*   token_ids = (const int*)d_in[0];   // B x L
    const int*   labels    = (const int*)d_in[1];   // B
    const float* emb       = (const float*)d_in[2]; // VOCAB x 256
    const float* W_w       = (const float*)d_in[3]; // 256 x 512
    const float* W_b       = (const float*)d_in[4]; // 256
    const float* P_w       = (const float*)d_in[5]; // 2 x 256
    const float* P_b       = (const float*)d_in[6]; // 2
    float*       out       = (float*)d_out;

    // ping-pong buffers in workspace:
    //   bufA: level-1 output, 131072 x 256 f32 = 134.2 MB (also levels 3,5,7,9)
    //   bufB: level-2 output,  65536 x 256 f32 =  67.1 MB (also levels 4,6,8,10)
    float* bufA = (float*)d_ws;
    float* bufB = bufA + (size_t)131072 * EMBED;

    const float* in = nullptr;
    int Rout = (BATCH * SEQ) / 2;   // 131072 output rows at level 1
    for (int lv = 1; lv <= 10; ++lv) {
        float* outbuf = (lv & 1) ? bufA : bufB;
        dim3 grid(Rout / BM, EMBED / BN);
        gemm_relu_kernel<<<grid, 256, 0, stream>>>(
            in, W_w, W_b, outbuf,
            (lv == 1) ? token_ids : nullptr, emb);
        in = outbuf;
        Rout >>= 1;
    }

    head_kernel<<<BATCH, 64, 0, stream>>>(in, P_w, P_b, labels, out);
}

// Round 4
// 551.618 us; speedup vs baseline: 2.5861x; 2.5861x over previous
//
#include <hip/hip_runtime.h>
#include <hip/hip_bf16.h>
#include <math.h>

#define EMBED   256
#define KDIM    512
#define BATCH   256

#define BM      128
#define BN      256
#define BK      32
#define THREADS 512

typedef float  f32x4   __attribute__((ext_vector_type(4)));
typedef __bf16 bf16x8  __attribute__((ext_vector_type(8)));
typedef unsigned short ushort8 __attribute__((ext_vector_type(8)));

__device__ __forceinline__ unsigned short f32_to_bf16_rne(float f) {
    unsigned int u = __float_as_uint(f);
    u += 0x7FFFu + ((u >> 16) & 1u);
    return (unsigned short)(u >> 16);
}
__device__ __forceinline__ float bf16_to_f32(unsigned short h) {
    return __uint_as_float(((unsigned int)h) << 16);
}

// async global->LDS, 16B per lane; dest = lds_base + lane*16 (wave-uniform base)
__device__ __forceinline__ void gload16(const void* g, void* l) {
    __builtin_amdgcn_global_load_lds(
        (const __attribute__((address_space(1))) unsigned int*)g,
        (__attribute__((address_space(3))) unsigned int*)l,
        16, 0, 0);
}

// Y[r,e] = relu( sum_k X[r,k] * W[e,k] + bias[e] ),  X: R x 512 (pair-concat of prev level),
// W: 256 x 512, Y: R x 256 stored as bf16 hi/lo pair.
// LV1: X synthesized from emb gather + relu (f32), reg-staged with on-the-fly hi/lo split.
// WPREP: W pre-split into bf16 Wh/Wl (global_load_lds staging); else reg-stage from f32 W.
template<int LV1, int WPREP>
__global__ __launch_bounds__(THREADS) void gemm_tree(
    const unsigned short* __restrict__ Xh, const unsigned short* __restrict__ Xl,
    const unsigned short* __restrict__ Wh, const unsigned short* __restrict__ Wl,
    const float*  __restrict__ Wf,
    const float*  __restrict__ bias,
    unsigned short* __restrict__ Yh, unsigned short* __restrict__ Yl,
    const int* __restrict__ tok, const float* __restrict__ emb)
{
    // fragment-order LDS: subtile s (16 rows x 32 k) = 512 ushort at s*512; lane slot = l*8
    __shared__ unsigned short Ah[4096], Al[4096];    // 128 x 32 hi/lo  (8 subtiles each)
    __shared__ unsigned short Bh[8192], Bl[8192];    // 256 x 32 hi/lo  (16 subtiles each)

    const int tid = threadIdx.x;
    const int wid = tid >> 6;          // 0..7
    const int l   = tid & 63;
    const int q   = l >> 4;            // k-chunk 0..3 (k = q*8 + i)
    const int rr  = l & 15;            // row/col within subtile
    const int m0  = blockIdx.x * BM;

    const int waveM = wid >> 2;        // 0..1  -> rows waveM*64 ..
    const int waveN = wid & 3;         // 0..3  -> cols waveN*64 ..

    f32x4 acc[4][4] = {};              // 4 M-frags x 4 N-frags x 4 f32

    for (int k0 = 0; k0 < KDIM; k0 += BK) {
        const int joff = k0 >> 8;              // which of the concat pair
        const int c    = (k0 & 255) + q * 8;   // col within source row

        // ---- stage A (wave wid owns subtile wid) ----
        if constexpr (LV1) {
            const int   j = 2 * (m0 + wid * 16 + rr) + joff;
            const int   t = tok[j];
            const float* e = emb + (size_t)t * EMBED + c;
            float v[8];
            *(float4*)&v[0] = *(const float4*)e;
            *(float4*)&v[4] = *(const float4*)(e + 4);
            ushort8 hs, ls;
            #pragma unroll
            for (int i = 0; i < 8; ++i) {
                float f = fmaxf(v[i], 0.f);
                unsigned short h = f32_to_bf16_rne(f);
                hs[i] = h;
                ls[i] = f32_to_bf16_rne(f - bf16_to_f32(h));
            }
            *(ushort8*)&Ah[wid * 512 + l * 8] = hs;
            *(ushort8*)&Al[wid * 512 + l * 8] = ls;
        } else {
            const size_t srow = (size_t)(2 * (m0 + wid * 16 + rr) + joff) * EMBED + c;
            gload16(Xh + srow, &Ah[wid * 512]);
            gload16(Xl + srow, &Al[wid * 512]);
        }

        // ---- stage B (wave wid owns subtiles wid and wid+8) ----
        #pragma unroll
        for (int h2 = 0; h2 < 2; ++h2) {
            const int sn = wid + h2 * 8;
            if constexpr (WPREP) {
                const size_t soff = (size_t)(sn * 16 + rr) * KDIM + k0 + q * 8;
                gload16(Wh + soff, &Bh[sn * 512]);
                gload16(Wl + soff, &Bl[sn * 512]);
            } else {
                const float* wsrc = Wf + (size_t)(sn * 16 + rr) * KDIM + k0 + q * 8;
                float v[8];
                *(float4*)&v[0] = *(const float4*)wsrc;
                *(float4*)&v[4] = *(const float4*)(wsrc + 4);
                ushort8 hs, ls;
                #pragma unroll
                for (int i = 0; i < 8; ++i) {
                    unsigned short h = f32_to_bf16_rne(v[i]);
                    hs[i] = h;
                    ls[i] = f32_to_bf16_rne(v[i] - bf16_to_f32(h));
                }
                *(ushort8*)&Bh[sn * 512 + l * 8] = hs;
                *(ushort8*)&Bl[sn * 512 + l * 8] = ls;
            }
        }

        __syncthreads();   // waits vmcnt(0)+lgkmcnt(0): staged data visible

        // ---- fragments + 3-pass split MFMA ----
        bf16x8 ah[4], al[4], bh[4], bl[4];
        #pragma unroll
        for (int mi = 0; mi < 4; ++mi) {
            ah[mi] = *(const bf16x8*)&Ah[(waveM * 4 + mi) * 512 + l * 8];
            al[mi] = *(const bf16x8*)&Al[(waveM * 4 + mi) * 512 + l * 8];
        }
        #pragma unroll
        for (int ni = 0; ni < 4; ++ni) {
            bh[ni] = *(const bf16x8*)&Bh[(waveN * 4 + ni) * 512 + l * 8];
            bl[ni] = *(const bf16x8*)&Bl[(waveN * 4 + ni) * 512 + l * 8];
        }
        #pragma unroll
        for (int mi = 0; mi < 4; ++mi)
            #pragma unroll
            for (int ni = 0; ni < 4; ++ni)
                acc[mi][ni] = __builtin_amdgcn_mfma_f32_16x16x32_bf16(ah[mi], bh[ni], acc[mi][ni], 0, 0, 0);
        #pragma unroll
        for (int mi = 0; mi < 4; ++mi)
            #pragma unroll
            for (int ni = 0; ni < 4; ++ni)
                acc[mi][ni] = __builtin_amdgcn_mfma_f32_16x16x32_bf16(al[mi], bh[ni], acc[mi][ni], 0, 0, 0);
        #pragma unroll
        for (int mi = 0; mi < 4; ++mi)
            #pragma unroll
            for (int ni = 0; ni < 4; ++ni)
                acc[mi][ni] = __builtin_amdgcn_mfma_f32_16x16x32_bf16(ah[mi], bl[ni], acc[mi][ni], 0, 0, 0);

        __syncthreads();   // all reads done before next-step overwrite
    }

    // ---- epilogue: bias + relu + hi/lo split store ----
    // C/D layout (m89-verified): col = l&15, row = (l>>4)*4 + jj
    #pragma unroll
    for (int ni = 0; ni < 4; ++ni) {
        const int col = waveN * 64 + ni * 16 + rr;
        const float bv = bias[col];
        #pragma unroll
        for (int mi = 0; mi < 4; ++mi) {
            const int row0 = m0 + waveM * 64 + mi * 16 + q * 4;
            #pragma unroll
            for (int jj = 0; jj < 4; ++jj) {
                float y = fmaxf(acc[mi][ni][jj] + bv, 0.f);
                unsigned short h = f32_to_bf16_rne(y);
                Yh[(size_t)(row0 + jj) * EMBED + col] = h;
                Yl[(size_t)(row0 + jj) * EMBED + col] = f32_to_bf16_rne(y - bf16_to_f32(h));
            }
        }
    }
}

__global__ __launch_bounds__(256) void prep_w(const float* __restrict__ W,
                                              unsigned short* __restrict__ Wh,
                                              unsigned short* __restrict__ Wl)
{
    const int i = blockIdx.x * 256 + threadIdx.x;   // 131072 elems
    const float w = W[i];
    const unsigned short h = f32_to_bf16_rne(w);
    Wh[i] = h;
    Wl[i] = f32_to_bf16_rne(w - bf16_to_f32(h));
}

// One wave per batch row: logits = root @ P_w^T + P_b; pred = argmax; loss = lse - logit[label]
__global__ __launch_bounds__(64) void head_kernel(
    const unsigned short* __restrict__ Xh, const unsigned short* __restrict__ Xl,
    const float* __restrict__ Pw, const float* __restrict__ Pb,
    const int* __restrict__ labels, float* __restrict__ out)
{
    const int b = blockIdx.x;
    const int lane = threadIdx.x;

    float s0 = 0.f, s1 = 0.f;
    #pragma unroll
    for (int i = 0; i < 4; ++i) {
        const int e = lane + i * 64;
        const float x = bf16_to_f32(Xh[(size_t)b * EMBED + e]) +
                        bf16_to_f32(Xl[(size_t)b * EMBED + e]);
        s0 = fmaf(x, Pw[e], s0);
        s1 = fmaf(x, Pw[EMBED + e], s1);
    }
    #pragma unroll
    for (int off = 32; off > 0; off >>= 1) {
        s0 += __shfl_down(s0, off);
        s1 += __shfl_down(s1, off);
    }
    if (lane == 0) {
        const float l0 = s0 + Pb[0];
        const float l1 = s1 + Pb[1];
        const int pred = (l1 > l0) ? 1 : 0;
        const float m = fmaxf(l0, l1);
        const float lse = m + logf(expf(l0 - m) + expf(l1 - m));
        const int lab = labels[b];
        out[b]         = (float)pred;
        out[BATCH + b] = lse - (lab ? l1 : l0);
    }
}

extern "C" void kernel_launch(void* const* d_in, const int* in_sizes, int n_in,
                              void* d_out, int out_size, void* d_ws, size_t ws_size,
                              hipStream_t stream)
{
    const int*   token_ids = (const int*)d_in[0];
    const int*   labels    = (const int*)d_in[1];
    const float* emb       = (const float*)d_in[2];
    const float* W_w       = (const float*)d_in[3];
    const float* W_b       = (const float*)d_in[4];
    const float* P_w       = (const float*)d_in[5];
    const float* P_b       = (const float*)d_in[6];
    float*       out       = (float*)d_out;

    // ws layout (ushort units):
    //   odd-level outputs:  Ah_buf/Al_buf  131072*256 each  (64 MiB each)
    //   even-level outputs: Bh_buf/Bl_buf   65536*256 each  (32 MiB each)
    //   W split:            Wh/Wl           131072 each     (256 KiB each)
    unsigned short* Ah_buf = (unsigned short*)d_ws;
    unsigned short* Al_buf = Ah_buf + (size_t)131072 * 256;
    unsigned short* Bh_buf = Al_buf + (size_t)131072 * 256;
    unsigned short* Bl_buf = Bh_buf + (size_t)65536 * 256;
    unsigned short* Wh     = Bl_buf + (size_t)65536 * 256;
    unsigned short* Wl     = Wh + 131072;

    const size_t need_wprep = ((size_t)131072 * 256 * 2 + (size_t)65536 * 256 * 2 + 2 * 131072) * 2;
    const bool wprep = ws_size >= need_wprep;

    if (wprep) prep_w<<<512, 256, 0, stream>>>(W_w, Wh, Wl);

    int R = 131072;
    const unsigned short *inh = nullptr, *inl = nullptr;
    for (int lv = 1; lv <= 10; ++lv) {
        unsigned short* yh = (lv & 1) ? Ah_buf : Bh_buf;
        unsigned short* yl = (lv & 1) ? Al_buf : Bl_buf;
        dim3 grid(R / BM);
        if (lv == 1) {
            if (wprep) gemm_tree<1,1><<<grid, THREADS, 0, stream>>>(nullptr, nullptr, Wh, Wl, W_w, W_b, yh, yl, token_ids, emb);
            else       gemm_tree<1,0><<<grid, THREADS, 0, stream>>>(nullptr, nullptr, Wh, Wl, W_w, W_b, yh, yl, token_ids, emb);
        } else {
            if (wprep) gemm_tree<0,1><<<grid, THREADS, 0, stream>>>(inh, inl, Wh, Wl, W_w, W_b, yh, yl, nullptr, nullptr);
            else       gemm_tree<0,0><<<grid, THREADS, 0, stream>>>(inh, inl, Wh, Wl, W_w, W_b, yh, yl, nullptr, nullptr);
        }
        inh = yh; inl = yl; R >>= 1;
    }

    head_kernel<<<BATCH, 64, 0, stream>>>(inh, inl, P_w, P_b, labels, out);
}

// Round 6
// 434.818 us; speedup vs baseline: 3.2807x; 1.2686x over previous
//
#include <hip/hip_runtime.h>
#include <hip/hip_bf16.h>
#include <math.h>

#define EMBED   256
#define KDIM    512
#define BATCH   256
#define BM      128

typedef float  f32x4   __attribute__((ext_vector_type(4)));
typedef __bf16 bf16x8  __attribute__((ext_vector_type(8)));
typedef unsigned short ushort8 __attribute__((ext_vector_type(8)));

__device__ __forceinline__ unsigned short f2h(float f) {
    unsigned int u = __float_as_uint(f);
    u += 0x7FFFu + ((u >> 16) & 1u);
    return (unsigned short)(u >> 16);
}
__device__ __forceinline__ float h2f(unsigned short h) {
    return __uint_as_float(((unsigned int)h) << 16);
}
// async global->LDS, 16B/lane; LDS dest = wave-uniform base + lane*16
__device__ __forceinline__ void gload16(const void* g, void* l) {
    __builtin_amdgcn_global_load_lds(
        (const __attribute__((address_space(1))) unsigned int*)g,
        (__attribute__((address_space(3))) unsigned int*)l, 16, 0, 0);
}

// ---------------- main tree GEMM (levels 1..5) ----------------
// Y[r,e] = relu(sum_k X[r,k]*W[e,k] + bias[e]); X rows synthesized by pair-concat.
// Split-bf16 (hi/lo) 3-pass MFMA. 2-phase pipeline: dbuf LDS, stage(t+1) issued
// before compute(t), ONE barrier per K-step.
template<int LV1, int WPREP>
__global__ __launch_bounds__(1024, 4) void gemm_tree(
    const unsigned short* __restrict__ Xh, const unsigned short* __restrict__ Xl,
    const unsigned short* __restrict__ Wh, const unsigned short* __restrict__ Wl,
    const float*  __restrict__ Wf,
    const float*  __restrict__ bias,
    unsigned short* __restrict__ Yh, unsigned short* __restrict__ Yl,
    const int* __restrict__ tok, const float* __restrict__ emb)
{
    // fragment-order LDS: subtile s = 16 rows x 32 k = 512 ushort at s*512, lane slot l*8
    __shared__ __align__(16) unsigned short AhL[2][4096], AlL[2][4096];   // 128x32 hi/lo
    __shared__ __align__(16) unsigned short BhL[2][8192], BlL[2][8192];   // 256x32 hi/lo

    const int tid = threadIdx.x;
    const int wid = tid >> 6;          // 0..15
    const int l   = tid & 63;
    const int q   = l >> 4;
    const int rr  = l & 15;
    const int m0  = blockIdx.x * BM;
    const int waveM = wid >> 2;        // 0..3 -> rows waveM*32..
    const int waveN = wid & 3;         // 0..3 -> cols waveN*64..

    int tokA0 = 0, tokA1 = 0;
    if constexpr (LV1) {
        if (wid < 8) {
            const int r = m0 + wid * 16 + rr;
            tokA0 = tok[2 * r];
            tokA1 = tok[2 * r + 1];
        }
    }

    float va[8];   // LV1 A gather regs (issue-early / convert-late)
    float vb[8];   // WPREP=0 W regs

    f32x4 acc[2][4] = {};

    auto stage_issue = [&](int buf, int k0) {
        const int joff = k0 >> 8;
        const int c    = (k0 & 255) + q * 8;
        if constexpr (LV1) {
            if (wid < 8) {
                const int t = joff ? tokA1 : tokA0;
                const float* e = emb + (size_t)t * EMBED + c;
                *(float4*)&va[0] = *(const float4*)e;
                *(float4*)&va[4] = *(const float4*)(e + 4);
            }
            if constexpr (WPREP) {
                #pragma unroll
                for (int j = 0; j < 2; ++j) {
                    const int sb = wid * 2 + j;          // 0..31
                    const int s  = sb & 15;
                    const size_t off = (size_t)(s * 16 + rr) * KDIM + k0 + q * 8;
                    if (sb < 16) gload16(Wh + off, &BhL[buf][s * 512]);
                    else         gload16(Wl + off, &BlL[buf][s * 512]);
                }
            } else {
                const float* ws = Wf + (size_t)(wid * 16 + rr) * KDIM + k0 + q * 8;
                *(float4*)&vb[0] = *(const float4*)ws;
                *(float4*)&vb[4] = *(const float4*)(ws + 4);
            }
        } else {
            if constexpr (WPREP) {
                #pragma unroll
                for (int j = 0; j < 3; ++j) {
                    const int slot = wid * 3 + j;        // 0..47
                    if (slot < 16) {                     // A: 0..7 hi, 8..15 lo
                        const int s = slot & 7;
                        const size_t off = (size_t)(2 * (m0 + s * 16 + rr) + joff) * EMBED + c;
                        if (slot < 8) gload16(Xh + off, &AhL[buf][s * 512]);
                        else          gload16(Xl + off, &AlL[buf][s * 512]);
                    } else {                             // B: 16..31 hi, 32..47 lo
                        const int s = slot & 15;
                        const size_t off = (size_t)(s * 16 + rr) * KDIM + k0 + q * 8;
                        if (slot < 32) gload16(Wh + off, &BhL[buf][s * 512]);
                        else           gload16(Wl + off, &BlL[buf][s * 512]);
                    }
                }
            } else {
                const int s = wid & 7;
                const size_t off = (size_t)(2 * (m0 + s * 16 + rr) + joff) * EMBED + c;
                if (wid < 8) gload16(Xh + off, &AhL[buf][s * 512]);
                else         gload16(Xl + off, &AlL[buf][s * 512]);
                const float* ws = Wf + (size_t)(wid * 16 + rr) * KDIM + k0 + q * 8;
                *(float4*)&vb[0] = *(const float4*)ws;
                *(float4*)&vb[4] = *(const float4*)(ws + 4);
            }
        }
    };

    auto stage_finish = [&](int buf) {
        if constexpr (LV1) {
            if (wid < 8) {
                ushort8 hs, ls;
                #pragma unroll
                for (int i = 0; i < 8; ++i) {
                    const float f = fmaxf(va[i], 0.f);
                    const unsigned short h = f2h(f);
                    hs[i] = h;
                    ls[i] = f2h(f - h2f(h));
                }
                *(ushort8*)&AhL[buf][wid * 512 + l * 8] = hs;
                *(ushort8*)&AlL[buf][wid * 512 + l * 8] = ls;
            }
        }
        if constexpr (!WPREP) {
            ushort8 hs, ls;
            #pragma unroll
            for (int i = 0; i < 8; ++i) {
                const unsigned short h = f2h(vb[i]);
                hs[i] = h;
                ls[i] = f2h(vb[i] - h2f(h));
            }
            *(ushort8*)&BhL[buf][wid * 512 + l * 8] = hs;
            *(ushort8*)&BlL[buf][wid * 512 + l * 8] = ls;
        }
    };

    // prologue: K-step 0 into buffer 0
    stage_issue(0, 0);
    stage_finish(0);
    __syncthreads();

    for (int t = 0; t < 16; ++t) {
        const int cur = t & 1;
        const int nxt = cur ^ 1;
        if (t < 15) stage_issue(nxt, (t + 1) << 5);

        bf16x8 ah[2], al[2], bh[4], bl[4];
        #pragma unroll
        for (int mi = 0; mi < 2; ++mi) {
            ah[mi] = *(const bf16x8*)&AhL[cur][(waveM * 2 + mi) * 512 + l * 8];
            al[mi] = *(const bf16x8*)&AlL[cur][(waveM * 2 + mi) * 512 + l * 8];
        }
        #pragma unroll
        for (int ni = 0; ni < 4; ++ni) {
            bh[ni] = *(const bf16x8*)&BhL[cur][(waveN * 4 + ni) * 512 + l * 8];
            bl[ni] = *(const bf16x8*)&BlL[cur][(waveN * 4 + ni) * 512 + l * 8];
        }
        #pragma unroll
        for (int mi = 0; mi < 2; ++mi)
            #pragma unroll
            for (int ni = 0; ni < 4; ++ni)
                acc[mi][ni] = __builtin_amdgcn_mfma_f32_16x16x32_bf16(ah[mi], bh[ni], acc[mi][ni], 0, 0, 0);
        #pragma unroll
        for (int mi = 0; mi < 2; ++mi)
            #pragma unroll
            for (int ni = 0; ni < 4; ++ni)
                acc[mi][ni] = __builtin_amdgcn_mfma_f32_16x16x32_bf16(al[mi], bh[ni], acc[mi][ni], 0, 0, 0);
        #pragma unroll
        for (int mi = 0; mi < 2; ++mi)
            #pragma unroll
            for (int ni = 0; ni < 4; ++ni)
                acc[mi][ni] = __builtin_amdgcn_mfma_f32_16x16x32_bf16(ah[mi], bl[ni], acc[mi][ni], 0, 0, 0);

        if (t < 15) stage_finish(nxt);
        __syncthreads();
    }

    // epilogue: bias + relu + hi/lo split store (C/D: col=l&15, row=(l>>4)*4+jj)
    #pragma unroll
    for (int ni = 0; ni < 4; ++ni) {
        const int col = waveN * 64 + ni * 16 + rr;
        const float bv = bias[col];
        #pragma unroll
        for (int mi = 0; mi < 2; ++mi) {
            const int row0 = m0 + waveM * 32 + mi * 16 + q * 4;
            #pragma unroll
            for (int jj = 0; jj < 4; ++jj) {
                const float y = fmaxf(acc[mi][ni][jj] + bv, 0.f);
                const unsigned short h = f2h(y);
                Yh[(size_t)(row0 + jj) * EMBED + col] = h;
                Yl[(size_t)(row0 + jj) * EMBED + col] = f2h(y - h2f(h));
            }
        }
    }
}

// ---------------- fused tail: levels 6..10 + head, one block per batch element ----------------
template<int WPREP>
__global__ __launch_bounds__(256) void tail_kernel(
    const unsigned short* __restrict__ Xh5, const unsigned short* __restrict__ Xl5,
    const unsigned short* __restrict__ Wh, const unsigned short* __restrict__ Wl,
    const float* __restrict__ Wf, const float* __restrict__ bias,
    const float* __restrict__ Pw, const float* __restrict__ Pb,
    const int* __restrict__ labels, float* __restrict__ out)
{
    // X buffers: row-major [rows][256] hi/lo, XOR-swizzled (ushort idx ^= (row&7)<<3)
    __shared__ __align__(16) unsigned short X0h[8192], X0l[8192];   // 32 rows
    __shared__ __align__(16) unsigned short X1h[4096], X1l[4096];   // 16 rows
    __shared__ __align__(16) unsigned short BhT[2][8192], BlT[2][8192];

    const int tid = threadIdx.x;
    const int w   = tid >> 6;      // 0..3
    const int l   = tid & 63;
    const int q   = l >> 4;
    const int rr  = l & 15;
    const int b   = blockIdx.x;

    // init X0 from level-5 output (swizzled ds_write; gload_lds can't swizzle)
    {
        const int row = tid >> 3;             // 0..31
        const int c0  = (tid & 7) * 32;
        #pragma unroll
        for (int i = 0; i < 4; ++i) {
            const int col = c0 + i * 8;
            const int sw  = (row * 256 + col) ^ ((row & 7) << 3);
            *(ushort8*)&X0h[sw] = *(const ushort8*)&Xh5[(size_t)(b * 32 + row) * EMBED + col];
            *(ushort8*)&X0l[sw] = *(const ushort8*)&Xl5[(size_t)(b * 32 + row) * EMBED + col];
        }
    }

    auto stageB = [&](int buf, int k0) {
        if constexpr (WPREP) {
            #pragma unroll
            for (int j = 0; j < 8; ++j) {
                const int sb = w * 8 + j;          // 0..31
                const int s  = sb & 15;
                const size_t off = (size_t)(s * 16 + rr) * KDIM + k0 + q * 8;
                if (sb < 16) gload16(Wh + off, &BhT[buf][s * 512]);
                else         gload16(Wl + off, &BlT[buf][s * 512]);
            }
        } else {
            #pragma unroll
            for (int j = 0; j < 4; ++j) {
                const int u = w * 4 + j;           // 0..15
                const float* ws = Wf + (size_t)(u * 16 + rr) * KDIM + k0 + q * 8;
                float v[8];
                *(float4*)&v[0] = *(const float4*)ws;
                *(float4*)&v[4] = *(const float4*)(ws + 4);
                ushort8 hs, ls;
                #pragma unroll
                for (int i = 0; i < 8; ++i) {
                    const unsigned short h = f2h(v[i]);
                    hs[i] = h;
                    ls[i] = f2h(v[i] - h2f(h));
                }
                *(ushort8*)&BhT[buf][u * 512 + l * 8] = hs;
                *(ushort8*)&BlT[buf][u * 512 + l * 8] = ls;
            }
        }
    };

    float bv[4];
    #pragma unroll
    for (int ni = 0; ni < 4; ++ni) bv[ni] = bias[w * 64 + ni * 16 + rr];

    stageB(0, 0);
    __syncthreads();

    int g = 0;
    for (int lv = 0; lv < 5; ++lv) {
        unsigned short* srch = (lv & 1) ? X1h : X0h;
        unsigned short* srcl = (lv & 1) ? X1l : X0l;
        unsigned short* dsth = (lv & 1) ? X0h : X1h;
        unsigned short* dstl = (lv & 1) ? X0l : X1l;
        const int Mout = 16 >> lv;

        f32x4 acc[4] = {};
        for (int t = 0; t < 16; ++t, ++g) {
            const int cur = g & 1;
            if (g < 79) stageB(cur ^ 1, ((t + 1) & 15) * 32);

            const int k0   = t * 32;
            const int joff = k0 >> 8;
            const int c    = (k0 & 255) + q * 8;
            const int row  = 2 * rr + joff;      // A row (stale beyond valid: harmless)
            const int idx  = (row * 256 + c) ^ ((row & 7) << 3);
            const bf16x8 a_h = *(const bf16x8*)&srch[idx];
            const bf16x8 a_l = *(const bf16x8*)&srcl[idx];

            bf16x8 bh4[4], bl4[4];
            #pragma unroll
            for (int ni = 0; ni < 4; ++ni) {
                bh4[ni] = *(const bf16x8*)&BhT[cur][(w * 4 + ni) * 512 + l * 8];
                bl4[ni] = *(const bf16x8*)&BlT[cur][(w * 4 + ni) * 512 + l * 8];
            }
            #pragma unroll
            for (int ni = 0; ni < 4; ++ni)
                acc[ni] = __builtin_amdgcn_mfma_f32_16x16x32_bf16(a_h, bh4[ni], acc[ni], 0, 0, 0);
            #pragma unroll
            for (int ni = 0; ni < 4; ++ni)
                acc[ni] = __builtin_amdgcn_mfma_f32_16x16x32_bf16(a_l, bh4[ni], acc[ni], 0, 0, 0);
            #pragma unroll
            for (int ni = 0; ni < 4; ++ni)
                acc[ni] = __builtin_amdgcn_mfma_f32_16x16x32_bf16(a_h, bl4[ni], acc[ni], 0, 0, 0);

            __syncthreads();
        }

        // epilogue: store valid rows only
        #pragma unroll
        for (int ni = 0; ni < 4; ++ni) {
            const int col = w * 64 + ni * 16 + rr;
            #pragma unroll
            for (int jj = 0; jj < 4; ++jj) {
                const int row = q * 4 + jj;
                if (row < Mout) {
                    const float y = fmaxf(acc[ni][jj] + bv[ni], 0.f);
                    const unsigned short h = f2h(y);
                    const int idx = (row * 256 + col) ^ ((row & 7) << 3);
                    dsth[idx] = h;
                    dstl[idx] = f2h(y - h2f(h));
                }
            }
        }
        __syncthreads();
    }

    // head: root = X1 row 0 (swizzle is identity for row 0)
    if (w == 0) {
        float s0 = 0.f, s1 = 0.f;
        #pragma unroll
        for (int i = 0; i < 4; ++i) {
            const int col = l + i * 64;
            const float x = h2f(X1h[col]) + h2f(X1l[col]);
            s0 = fmaf(x, Pw[col], s0);
            s1 = fmaf(x, Pw[EMBED + col], s1);
        }
        #pragma unroll
        for (int off = 32; off > 0; off >>= 1) {
            s0 += __shfl_down(s0, off);
            s1 += __shfl_down(s1, off);
        }
        if (l == 0) {
            const float l0 = s0 + Pb[0];
            const float l1 = s1 + Pb[1];
            const int pred = (l1 > l0) ? 1 : 0;
            const float m  = fmaxf(l0, l1);
            const float lse = m + logf(expf(l0 - m) + expf(l1 - m));
            const int lab = labels[b];
            out[b]         = (float)pred;
            out[BATCH + b] = lse - (lab ? l1 : l0);
        }
    }
}

__global__ __launch_bounds__(256) void prep_w(const float* __restrict__ W,
                                              unsigned short* __restrict__ Wh,
                                              unsigned short* __restrict__ Wl)
{
    const int i = blockIdx.x * 256 + threadIdx.x;   // 131072 elems
    const float w = W[i];
    const unsigned short h = f2h(w);
    Wh[i] = h;
    Wl[i] = f2h(w - h2f(h));
}

extern "C" void kernel_launch(void* const* d_in, const int* in_sizes, int n_in,
                              void* d_out, int out_size, void* d_ws, size_t ws_size,
                              hipStream_t stream)
{
    const int*   token_ids = (const int*)d_in[0];
    const int*   labels    = (const int*)d_in[1];
    const float* emb       = (const float*)d_in[2];
    const float* W_w       = (const float*)d_in[3];
    const float* W_b       = (const float*)d_in[4];
    const float* P_w       = (const float*)d_in[5];
    const float* P_b       = (const float*)d_in[6];
    float*       out       = (float*)d_out;

    unsigned short* Ah_buf = (unsigned short*)d_ws;
    unsigned short* Al_buf = Ah_buf + (size_t)131072 * 256;
    unsigned short* Bh_buf = Al_buf + (size_t)131072 * 256;
    unsigned short* Bl_buf = Bh_buf + (size_t)65536 * 256;
    unsigned short* Wh     = Bl_buf + (size_t)65536 * 256;
    unsigned short* Wl     = Wh + 131072;

    const size_t need_wprep = ((size_t)131072 * 256 * 2 + (size_t)65536 * 256 * 2 + 2 * 131072) * 2;
    const bool wprep = ws_size >= need_wprep;

    if (wprep) prep_w<<<512, 256, 0, stream>>>(W_w, Wh, Wl);

    int R = 131072;
    const unsigned short *inh = nullptr, *inl = nullptr;
    for (int lv = 1; lv <= 5; ++lv) {
        unsigned short* yh = (lv & 1) ? Ah_buf : Bh_buf;
        unsigned short* yl = (lv & 1) ? Al_buf : Bl_buf;
        dim3 grid(R / BM);
        if (lv == 1) {
            if (wprep) gemm_tree<1,1><<<grid, 1024, 0, stream>>>(nullptr, nullptr, Wh, Wl, W_w, W_b, yh, yl, token_ids, emb);
            else       gemm_tree<1,0><<<grid, 1024, 0, stream>>>(nullptr, nullptr, Wh, Wl, W_w, W_b, yh, yl, token_ids, emb);
        } else {
            if (wprep) gemm_tree<0,1><<<grid, 1024, 0, stream>>>(inh, inl, Wh, Wl, W_w, W_b, yh, yl, nullptr, nullptr);
            else       gemm_tree<0,0><<<grid, 1024, 0, stream>>>(inh, inl, Wh, Wl, W_w, W_b, yh, yl, nullptr, nullptr);
        }
        inh = yh; inl = yl; R >>= 1;
    }

    if (wprep) tail_kernel<1><<<BATCH, 256, 0, stream>>>(inh, inl, Wh, Wl, W_w, W_b, P_w, P_b, labels, out);
    else       tail_kernel<0><<<BATCH, 256, 0, stream>>>(inh, inl, Wh, Wl, W_w, W_b, P_w, P_b, labels, out);
}